// Round 1
// baseline (241.710 us; speedup 1.0000x reference)
//
#include <hip/hip_runtime.h>
#include <hip/hip_bf16.h>
#include <stdint.h>

#define NUM_MODALS 4
#define SHARED_IDX 3

typedef __attribute__((ext_vector_type(8))) short bf16x8;
typedef __attribute__((ext_vector_type(4))) float floatx4;

__device__ __forceinline__ unsigned short f2bf(float f) {
  unsigned int u = __float_as_uint(f);
  u += 0x7fffu + ((u >> 16) & 1u);   // round-to-nearest-even
  return (unsigned short)(u >> 16);
}

// ---------------- W_eff build (latency-fixed) ----------------
// W_eff[m][o][c] = Wp[o][c] + sum_r Bw[3][o][r]*A[3][r][c] + sum_r Bw[m][o][r]*A[m][r][c]
__global__ __launch_bounds__(256) void weff_fast(
    const float* __restrict__ Wp, const float* __restrict__ A,
    const float* __restrict__ Bw, unsigned short* __restrict__ Weff) {
  const int c  = blockIdx.x * 256 + threadIdx.x;
  const int o0 = blockIdx.y * 16;
  const int m  = blockIdx.z;

  __shared__ float b3[256], bm[256];   // 16 o-rows x 16 r, both adapters
  const int t = threadIdx.x;
  {
    const int o = o0 + (t >> 4);
    const int r = t & 15;
    b3[t] = Bw[(SHARED_IDX * 768 + o) * 16 + r];
    bm[t] = Bw[((size_t)m * 768 + o) * 16 + r];
  }
  __syncthreads();

  float a3[16], am[16];
#pragma unroll
  for (int r = 0; r < 16; ++r) {
    a3[r] = A[(SHARED_IDX * 16 + r) * 768 + c];
    am[r] = A[((size_t)m * 16 + r) * 768 + c];
  }
#pragma unroll 4
  for (int oo = 0; oo < 16; ++oo) {
    const int o = o0 + oo;
    float acc = Wp[(size_t)o * 768 + c];
#pragma unroll
    for (int r = 0; r < 16; ++r) {
      acc += b3[oo * 16 + r] * a3[r];
      acc += bm[oo * 16 + r] * am[r];
    }
    Weff[((size_t)m * 768 + o) * 768 + c] = f2bf(acc);
  }
}

// ---------------- fused GEMM: out[m] = X[m] (fp32, cvt in-reg) * Weff[m]^T + bp ----
// 128x128 tile, BK=64, 4 waves x 4x4 16x16x32-bf16 frags.
// NEW (this round): 1-deep software pipeline with double-buffered LDS and ONE
// barrier per K-step. X(kt+1) float4s and W(kt+1) global_load_lds are issued a
// full compute phase before they are consumed, so neither global-load latency
// sits on the barrier-to-barrier critical path anymore. Buffer parity:
// compute(kt) reads buf[kt&1] while staging(kt+1) targets buf[(kt+1)&1], so the
// single __syncthreads per step (which drains vmcnt(0)/lgkmcnt(0)) is the only
// ordering point needed: it retires W(kt) glds (issued one phase ago) and makes
// all As[b] ds_writes visible, and the lgkm drain guarantees nobody still reads
// the opposite buffer when we overwrite it.
__global__ __launch_bounds__(256) void lora_gemm_fused(
    const float* __restrict__ X,
    const unsigned short* __restrict__ Weff,
    const float* __restrict__ bp,
    float* __restrict__ out) {
  const int bid = blockIdx.x;
  const int xcd = bid & 7;
  const int s   = bid >> 3;          // 0..191
  const int w   = xcd * 192 + s;     // contiguous per-XCD chunk
  const int ct  = w % 6;
  const int rt  = w / 6;             // 0..255
  const int m        = rt >> 6;
  const int row_base = (rt & 63) * 128;
  const int col_base = ct * 128;

  // double-buffered: [2][128][64] bf16 each
  __shared__ alignas(16) unsigned short As[2 * 128 * 64];
  __shared__ alignas(16) unsigned short Ws[2 * 128 * 64];

  const int tid  = threadIdx.x;
  const int wave = tid >> 6;
  const int lane = tid & 63;
  const int ln = lane & 15;
  const int qd = lane >> 4;
  const int wm = wave & 1;
  const int wn = wave >> 1;

  const float*          Xm = X    + (size_t)m * 8192 * 768;
  const unsigned short* Wm = Weff + (size_t)m * 768 * 768;

  floatx4 acc[4][4];
#pragma unroll
  for (int i = 0; i < 4; ++i)
#pragma unroll
    for (int j = 0; j < 4; ++j)
      acc[i][j] = (floatx4)(0.0f);

  // --- X staging geometry: thread covers (row xr+p*16, 4 fp32 cols at xc) ---
  const int xr   = tid >> 4;         // 0..15
  const int xc   = (tid & 15) * 4;   // 0..60
  const int cb   = xc >> 3;          // 16B col-block 0..7
  const int half = (xc >> 2) & 1;    // which 8B half of the block
  const float* xsrc[8];
  unsigned short* xdst[8];           // into buffer 0; add boff for buffer 1
#pragma unroll
  for (int p = 0; p < 8; ++p) {
    const int r = xr + p * 16;
    xsrc[p] = Xm + (size_t)(row_base + r) * 768 + xc;
    xdst[p] = &As[r * 64 + (cb ^ (r & 7)) * 8 + half * 4];
  }
  // --- W staging geometry (global_load_lds: 8 rows x 128 B per issue) ---
  const int sr = lane >> 3;          // row-in-8
  const int ss = lane & 7;           // LDS slot this lane fills
  const unsigned short* wsrc[4];
#pragma unroll
  for (int p = 0; p < 4; ++p) {
    const int r = wave * 32 + p * 8 + sr;
    wsrc[p] = Wm + (size_t)(col_base + r) * 768 + (ss ^ (r & 7)) * 8;
  }

  // ---- prologue: issue X(0) -> regs, W(0) -> Ws[buf0] ----
  float4 xv[8];
#pragma unroll
  for (int p = 0; p < 8; ++p) {
    xv[p] = *(const float4*)xsrc[p];
    xsrc[p] += 64;
  }
#pragma unroll
  for (int p = 0; p < 4; ++p) {
    __builtin_amdgcn_global_load_lds(
        (const __attribute__((address_space(1))) void*)wsrc[p],
        (__attribute__((address_space(3))) void*)&Ws[(wave * 32 + p * 8) * 64],
        16, 0, 0);
    wsrc[p] += 64;
  }

  for (int kt = 0; kt < 12; ++kt) {
    const int boff = (kt & 1) * (128 * 64);

    // convert + write X(kt) into As[b] (xv loads were issued one phase ago)
#pragma unroll
    for (int p = 0; p < 8; ++p) {
      const float4 v = xv[p];
      __hip_bfloat162 h0 = __float22bfloat162_rn(make_float2(v.x, v.y));
      __hip_bfloat162 h1 = __float22bfloat162_rn(make_float2(v.z, v.w));
      uint2 hv;
      hv.x = *(unsigned int*)&h0;
      hv.y = *(unsigned int*)&h1;
      *(uint2*)(xdst[p] + boff) = hv;
    }

    // single barrier per K-step: drains W(kt) glds (vmcnt) + As[b] writes (lgkm),
    // and guarantees everyone is done reading the opposite buffer.
    __syncthreads();

    if (kt < 11) {
      const int nboff = boff ^ (128 * 64);
      // issue X(kt+1) -> regs
#pragma unroll
      for (int p = 0; p < 8; ++p) {
        xv[p] = *(const float4*)xsrc[p];
        xsrc[p] += 64;
      }
      // issue W(kt+1) -> Ws[b^1]
#pragma unroll
      for (int p = 0; p < 4; ++p) {
        __builtin_amdgcn_global_load_lds(
            (const __attribute__((address_space(1))) void*)wsrc[p],
            (__attribute__((address_space(3))) void*)&Ws[nboff + (wave * 32 + p * 8) * 64],
            16, 0, 0);
        wsrc[p] += 64;
      }
      // pin the prefetch issues here: don't let the scheduler sink them below
      // the MFMA phase (that would re-expose the global latency).
      __builtin_amdgcn_sched_barrier(0);
    }

    // compute(kt) on buffer b
#pragma unroll
    for (int kk = 0; kk < 64; kk += 32) {
      const int kblk = (kk >> 3) + qd;           // 0..7
      const int slot = (kblk ^ (ln & 7)) * 8;
      bf16x8 a[4], b[4];
#pragma unroll
      for (int i = 0; i < 4; ++i)
        a[i] = *(const bf16x8*)(&As[boff + (wm * 64 + i * 16 + ln) * 64 + slot]);
#pragma unroll
      for (int j = 0; j < 4; ++j)
        b[j] = *(const bf16x8*)(&Ws[boff + (wn * 64 + j * 16 + ln) * 64 + slot]);
#pragma unroll
      for (int i = 0; i < 4; ++i)
#pragma unroll
        for (int j = 0; j < 4; ++j)
          acc[i][j] = __builtin_amdgcn_mfma_f32_16x16x32_bf16(a[i], b[j], acc[i][j], 0, 0, 0);
    }
  }

  float* Om = out + (size_t)m * 8192 * 768;
#pragma unroll
  for (int j = 0; j < 4; ++j) {
    const int o = col_base + wn * 64 + j * 16 + ln;
    const float bias = bp[o];
#pragma unroll
    for (int i = 0; i < 4; ++i) {
      const int R = row_base + wm * 64 + i * 16 + qd * 4;
      float* dst = Om + (size_t)R * 768 + o;
#pragma unroll
      for (int v = 0; v < 4; ++v)
        dst[(size_t)v * 768] = acc[i][j][v] + bias;
    }
  }
}

extern "C" void kernel_launch(void* const* d_in, const int* in_sizes, int n_in,
                              void* d_out, int out_size, void* d_ws, size_t ws_size,
                              hipStream_t stream) {
  const float* x  = (const float*)d_in[0];   // [32, 1024, 768]
  const float* Wp = (const float*)d_in[1];   // [768, 768]
  const float* bp = (const float*)d_in[2];   // [768]
  const float* A  = (const float*)d_in[3];   // [4, 16, 768]
  const float* Bw = (const float*)d_in[4];   // [4, 768, 16]
  float* out = (float*)d_out;                // [32, 1024, 768]

  unsigned short* Weff = (unsigned short*)d_ws;  // [4][768][768] bf16 = 4.5 MB

  weff_fast<<<dim3(3, 48, 4), 256, 0, stream>>>(Wp, A, Bw, Weff);
  lora_gemm_fused<<<dim3(1536), 256, 0, stream>>>(x, Weff, bp, out);
}